// Round 8
// baseline (360.210 us; speedup 1.0000x reference)
//
#include <hip/hip_runtime.h>
#include <hip/hip_bf16.h>
#include <math.h>

typedef __hip_bfloat16 bf16;
typedef __attribute__((ext_vector_type(8))) short bf16x8;
typedef __attribute__((ext_vector_type(4))) float f32x4;

__device__ __forceinline__ unsigned short f2bf_rne(float f) {
  unsigned u = __float_as_uint(f);
  u += 0x7fffu + ((u >> 16) & 1u);
  return (unsigned short)(u >> 16);
}
__device__ __forceinline__ float bf2f(unsigned short s) {
  return __uint_as_float(((unsigned)s) << 16);
}

// fast tanh-form GELU: max |diff| vs exact erf-GELU ~1e-3
__device__ __forceinline__ float gelu_fast(float v) {
  float u = v * (0.7978845608f + 0.0356774081f * v * v);
  float t = __builtin_amdgcn_exp2f(u * 2.8853900818f);
  float r = __builtin_amdgcn_rcpf(t + 1.0f);
  return v - v * r;
}

#define GLOBAL_AS __attribute__((address_space(1)))
#define LDS_AS __attribute__((address_space(3)))
__device__ __forceinline__ void gl2lds16(const void* g, void* l) {
  __builtin_amdgcn_global_load_lds((const GLOBAL_AS void*)g, (LDS_AS void*)l, 16, 0, 0);
}

// ---------------- LayerNorm: x f32 [rows][1024] -> h bf16 ----------------
__global__ __launch_bounds__(256) void ln_kernel(const float* __restrict__ x,
                                                 const float* __restrict__ g,
                                                 const float* __restrict__ b,
                                                 bf16* __restrict__ h) {
  int row = blockIdx.x, t = threadIdx.x;
  const float4 xv = ((const float4*)(x + (size_t)row * 1024))[t];
  float s = xv.x + xv.y + xv.z + xv.w;
  float sq = xv.x * xv.x + xv.y * xv.y + xv.z * xv.z + xv.w * xv.w;
  #pragma unroll
  for (int m = 1; m < 64; m <<= 1) { s += __shfl_xor(s, m); sq += __shfl_xor(sq, m); }
  __shared__ float ps[4], pq[4];
  if ((t & 63) == 0) { ps[t >> 6] = s; pq[t >> 6] = sq; }
  __syncthreads();
  s = ps[0] + ps[1] + ps[2] + ps[3];
  sq = pq[0] + pq[1] + pq[2] + pq[3];
  float mean = s * (1.0f / 1024.0f);
  float var = sq * (1.0f / 1024.0f) - mean * mean;
  float rs = rsqrtf(var + 1e-3f);
  float4 gv = ((const float4*)g)[t];
  float4 bv = ((const float4*)b)[t];
  ushort4 o;
  o.x = f2bf_rne((xv.x - mean) * rs * gv.x + bv.x);
  o.y = f2bf_rne((xv.y - mean) * rs * gv.y + bv.y);
  o.z = f2bf_rne((xv.z - mean) * rs * gv.z + bv.z);
  o.w = f2bf_rne((xv.w - mean) * rs * gv.w + bv.w);
  ((ushort4*)(h + (size_t)row * 1024))[t] = o;
}

// ------------- merged transpose + f32->bf16 for all 5 weights -------------
__device__ __forceinline__ void tr_tile(const float* __restrict__ W, bf16* __restrict__ WT,
                                        int R, int Cc, int bx, int by, int t) {
  __shared__ float tile[32][33];
  int tx = t & 31, ty = t >> 5;
  #pragma unroll
  for (int k = 0; k < 4; k++) {
    int rr = ty + k * 8;
    tile[rr][tx] = W[(size_t)(by + rr) * Cc + bx + tx];
  }
  __syncthreads();
  unsigned short* out = reinterpret_cast<unsigned short*>(WT);
  #pragma unroll
  for (int k = 0; k < 4; k++) {
    int rr = ty + k * 8;
    out[(size_t)(bx + rr) * R + by + tx] = f2bf_rne(tile[tx][rr]);
  }
}

__global__ __launch_bounds__(256) void transpose_all(const float* __restrict__ Wq,
                                                     const float* __restrict__ Wk,
                                                     const float* __restrict__ Wv,
                                                     const float* __restrict__ W1,
                                                     const float* __restrict__ W2,
                                                     bf16* __restrict__ WqkT,
                                                     bf16* __restrict__ W1T,
                                                     bf16* __restrict__ W2T) {
  int id = blockIdx.x, t = threadIdx.x;
  if (id < 3072) {
    int sect = id >> 10, r = id & 1023;
    const float* W = sect == 0 ? Wq : (sect == 1 ? Wk : Wv);
    bf16* WT = WqkT + (size_t)sect * 1048576;
    tr_tile(W, WT, 1024, 1024, (r & 31) * 32, (r >> 5) * 32, t);
  } else if (id < 7168) {
    int r = id - 3072;
    tr_tile(W1, W1T, 1024, 4096, (r & 127) * 32, (r >> 7) * 32, t);
  } else {
    int r = id - 7168;
    tr_tile(W2, W2T, 4096, 1024, (r & 31) * 32, (r >> 5) * 32, t);
  }
}

// ---------- shared K-loop: 128x128 tile, BK=64, async staging, XOR swizzle ----
__device__ __forceinline__ void kloop_bk64(const bf16* __restrict__ A,
                                           const bf16* __restrict__ BT,
                                           int K, int kbeg, int kend, int m0, int n0,
                                           int wave, int lane,
                                           bf16 (*As)[64], bf16 (*Bs)[64],
                                           f32x4 acc[4][4]) {
  int lrow = lane & 15, quad = lane >> 4;
  int wm = (wave >> 1) * 64, wn = (wave & 1) * 64;
  int srow = wave * 32 + (lane >> 3);
  int gsw = ((lane & 7) ^ (lane >> 3)) * 8;
  int sw = lrow & 7;
  for (int k0 = kbeg; k0 < kend; k0 += 64) {
    __syncthreads();
    #pragma unroll
    for (int j = 0; j < 4; j++) {
      int row = srow + j * 8;
      gl2lds16(A + (size_t)(m0 + row) * K + k0 + gsw, (char*)As + wave * 4096 + j * 1024);
      gl2lds16(BT + (size_t)(n0 + row) * K + k0 + gsw, (char*)Bs + wave * 4096 + j * 1024);
    }
    __syncthreads();
    bf16x8 af[2][4], bfr[2][4];
    #pragma unroll
    for (int h = 0; h < 2; h++) {
      #pragma unroll
      for (int i = 0; i < 4; i++)
        af[h][i] = *(const bf16x8*)((const char*)&As[wm + i * 16 + lrow][0] +
                                    (((h * 4 + quad) ^ sw) * 16));
      #pragma unroll
      for (int j = 0; j < 4; j++)
        bfr[h][j] = *(const bf16x8*)((const char*)&Bs[wn + j * 16 + lrow][0] +
                                     (((h * 4 + quad) ^ sw) * 16));
    }
    #pragma unroll
    for (int h = 0; h < 2; h++)
      #pragma unroll
      for (int i = 0; i < 4; i++)
        #pragma unroll
        for (int j = 0; j < 4; j++)
          acc[i][j] = __builtin_amdgcn_mfma_f32_16x16x32_bf16(af[h][i], bfr[h][j], acc[i][j], 0, 0, 0);
  }
}

// ---------------- FFN1: act bf16 = gelu(h @ W1 + b1), N=4096 K=1024 ---------
__global__ __launch_bounds__(256) void gemm_ffn1(const bf16* __restrict__ A,
                                                 const bf16* __restrict__ BT,
                                                 const float* __restrict__ bias,
                                                 bf16* __restrict__ out,
                                                 int N, int K) {
  __shared__ bf16 As[128][64];
  __shared__ bf16 Bs[128][64];
  int t = threadIdx.x;
  int n0 = blockIdx.x * 128, m0 = blockIdx.y * 128;
  int lane = t & 63, wave = t >> 6;
  f32x4 acc[4][4];
  #pragma unroll
  for (int i = 0; i < 4; i++)
    #pragma unroll
    for (int j = 0; j < 4; j++) acc[i][j] = (f32x4){0.f, 0.f, 0.f, 0.f};
  kloop_bk64(A, BT, K, 0, K, m0, n0, wave, lane, As, Bs, acc);

  int wm = (wave >> 1) * 64, wn = (wave & 1) * 64;
  int r4 = (lane >> 4) * 4, cl = lane & 15;
  unsigned short* os = reinterpret_cast<unsigned short*>(out);
  #pragma unroll
  for (int i = 0; i < 4; i++)
    #pragma unroll
    for (int j = 0; j < 4; j++) {
      int col = n0 + wn + j * 16 + cl;
      float bval = bias[col];
      #pragma unroll
      for (int r = 0; r < 4; r++) {
        int row = m0 + wm + i * 16 + r4 + r;
        os[(size_t)row * N + col] = f2bf_rne(gelu_fast(acc[i][j][r] + bval));
      }
    }
}

// ------- FFN2 split-K: partial bf16 = act[:, kslice] @ W2[kslice, :] --------
__global__ __launch_bounds__(256) void gemm_ffn2_sk(const bf16* __restrict__ A,
                                                    const bf16* __restrict__ BT,
                                                    unsigned short* __restrict__ p0,
                                                    unsigned short* __restrict__ p1,
                                                    int K) {
  __shared__ bf16 As[128][64];
  __shared__ bf16 Bs[128][64];
  int t = threadIdx.x;
  int n0 = blockIdx.x * 128, m0 = blockIdx.y * 128;
  int z = blockIdx.z;
  int lane = t & 63, wave = t >> 6;
  f32x4 acc[4][4];
  #pragma unroll
  for (int i = 0; i < 4; i++)
    #pragma unroll
    for (int j = 0; j < 4; j++) acc[i][j] = (f32x4){0.f, 0.f, 0.f, 0.f};
  kloop_bk64(A, BT, K, z * 2048, z * 2048 + 2048, m0, n0, wave, lane, As, Bs, acc);

  unsigned short* p = z ? p1 : p0;
  int wm = (wave >> 1) * 64, wn = (wave & 1) * 64;
  int r4 = (lane >> 4) * 4, cl = lane & 15;
  #pragma unroll
  for (int i = 0; i < 4; i++)
    #pragma unroll
    for (int j = 0; j < 4; j++) {
      int col = n0 + wn + j * 16 + cl;
      #pragma unroll
      for (int r = 0; r < 4; r++) {
        int row = m0 + wm + i * 16 + r4 + r;
        p[(size_t)row * 1024 + col] = f2bf_rne(acc[i][j][r]);
      }
    }
}

// -------- FFN2 reduce: out f32 = p0 + p1 + bias + x1 --------
__global__ __launch_bounds__(256) void reduce_ffn2(const unsigned short* __restrict__ p0,
                                                   const unsigned short* __restrict__ p1,
                                                   const float* __restrict__ x1,
                                                   const float* __restrict__ bias,
                                                   float* __restrict__ out) {
  int row = blockIdx.x, t = threadIdx.x;
  size_t base = (size_t)row * 1024;
  ushort4 a = ((const ushort4*)(p0 + base))[t];
  ushort4 b = ((const ushort4*)(p1 + base))[t];
  float4 xv = ((const float4*)(x1 + base))[t];
  float4 bv = ((const float4*)bias)[t];
  float4 o;
  o.x = bf2f(a.x) + bf2f(b.x) + xv.x + bv.x;
  o.y = bf2f(a.y) + bf2f(b.y) + xv.y + bv.y;
  o.z = bf2f(a.z) + bf2f(b.z) + xv.z + bv.z;
  o.w = bf2f(a.w) + bf2f(b.w) + xv.w + bv.w;
  ((float4*)(out + base))[t] = o;
}

// ------------- fused QKV GEMM: N=3072 (q|k|v); v written transposed ----------
__global__ __launch_bounds__(256) void gemm_qkv(const bf16* __restrict__ A,
                                                const bf16* __restrict__ BT,
                                                const float* __restrict__ bq,
                                                const float* __restrict__ bk,
                                                const float* __restrict__ bv,
                                                bf16* __restrict__ qb,
                                                bf16* __restrict__ kb,
                                                bf16* __restrict__ vt,
                                                int K) {
  __shared__ bf16 As[128][64];
  __shared__ bf16 Bs[128][64];
  int t = threadIdx.x;
  int n0 = blockIdx.x * 128, m0 = blockIdx.y * 128;
  int lane = t & 63, wave = t >> 6;
  f32x4 acc[4][4];
  #pragma unroll
  for (int i = 0; i < 4; i++)
    #pragma unroll
    for (int j = 0; j < 4; j++) acc[i][j] = (f32x4){0.f, 0.f, 0.f, 0.f};
  kloop_bk64(A, BT, K, 0, K, m0, n0, wave, lane, As, Bs, acc);

  int sect = n0 >> 10;  // 0=q 1=k 2=v
  const float* bias = sect == 0 ? bq : (sect == 1 ? bk : bv);
  int wm = (wave >> 1) * 64, wn = (wave & 1) * 64;
  int r4 = (lane >> 4) * 4, cl = lane & 15;
  #pragma unroll
  for (int i = 0; i < 4; i++)
    #pragma unroll
    for (int j = 0; j < 4; j++) {
      int col = n0 + wn + j * 16 + cl;
      int c1 = col & 1023;
      float bval = bias[c1];
      int row0 = m0 + wm + i * 16 + r4;
      if (sect < 2) {
        bf16* o = sect == 0 ? qb : kb;
        unsigned short* os = reinterpret_cast<unsigned short*>(o);
        #pragma unroll
        for (int r = 0; r < 4; r++)
          os[(size_t)(row0 + r) * 1024 + c1] = f2bf_rne(acc[i][j][r] + bval);
      } else {
        int hh = c1 >> 6, d = c1 & 63;
        int b = row0 >> 11, t0 = row0 & 2047;
        ushort4 pk;
        pk.x = f2bf_rne(acc[i][j][0] + bval);
        pk.y = f2bf_rne(acc[i][j][1] + bval);
        pk.z = f2bf_rne(acc[i][j][2] + bval);
        pk.w = f2bf_rne(acc[i][j][3] + bval);
        *(ushort4*)((unsigned short*)vt + (size_t)((b * 16 + hh) * 64 + d) * 2048 + t0) = pk;
      }
    }
}

// ---------------- MFMA flash attention v3 ----------------
// 128-row i-tile, one i-tile per block (grid 32x16 = 512 blocks = 2/CU).
// it = y<8 ? y : 23-y so co-resident blocks n,n+256 (XCD round-robin) get
// complementary work (2it+2)+(2(15-it)+2) = 34 j-units -> uniform CU load.
// P aliases Qe's LDS (qf fragments live in registers after prologue).
__global__ __launch_bounds__(256) void attn_mfma(const bf16* __restrict__ qb,
                                                 const bf16* __restrict__ kb,
                                                 const bf16* __restrict__ vt,
                                                 const float* __restrict__ x,
                                                 float* __restrict__ x1) {
  __shared__ bf16 QP[128][72];  // Qe in prologue, P during jt loop
  __shared__ bf16 Ke[64][72];
  __shared__ bf16 Vt[64][72];
  int t = threadIdx.x;
  int bh = blockIdx.x;
  int b = bh >> 4, h = bh & 15;
  size_t qk_base = (size_t)b * 2048 * 1024 + (size_t)h * 64;
  size_t vt_base = (size_t)bh * 64 * 2048;
  int lane = t & 63, wave = t >> 6;
  int l = lane & 15, quad = lane >> 4;
  const float cs = 0.125f * 1.44269504088896f;  // scale * log2(e)
  int y = blockIdx.y;
  int it = (y < 8) ? y : 23 - y;
  int i0 = it * 128;

  #pragma unroll
  for (int c0 = 0; c0 < 1024; c0 += 256) {
    int c = c0 + t;
    int row = c >> 3, col8 = (c & 7) * 8;
    *(uint4*)&QP[row][col8] = *(const uint4*)(kb + qk_base + (size_t)(i0 + row) * 1024 + col8);
  }
  __syncthreads();
  bf16x8 qf[2][2];
  #pragma unroll
  for (int s = 0; s < 2; s++) {
    int ib = (wave * 2 + s) * 16;
    qf[s][0] = *(const bf16x8*)&QP[ib + l][quad * 8];
    qf[s][1] = *(const bf16x8*)&QP[ib + l][32 + quad * 8];
  }
  float lsum[2] = {0.f, 0.f};
  f32x4 Oacc[2][4];
  #pragma unroll
  for (int s = 0; s < 2; s++)
    #pragma unroll
    for (int dt = 0; dt < 4; dt++) Oacc[s][dt] = (f32x4){0.f, 0.f, 0.f, 0.f};

  int njt = 2 * it + 2;
  for (int jt = 0; jt < njt; jt++) {
    int j0v = jt * 64;
    __syncthreads();  // prev iteration's Ke/Vt reads done (and prologue qf)
    #pragma unroll
    for (int c0 = 0; c0 < 512; c0 += 256) {
      int c = c0 + t;
      int row = c >> 3, col8 = (c & 7) * 8;
      *(uint4*)&Ke[row][col8] = *(const uint4*)(qb + qk_base + (size_t)(j0v + row) * 1024 + col8);
      *(uint4*)&Vt[row][col8] = *(const uint4*)(vt + vt_base + (size_t)row * 2048 + j0v + col8);
    }
    __syncthreads();

    #pragma unroll
    for (int nt = 0; nt < 4; nt++) {
      bf16x8 kf0 = *(const bf16x8*)&Ke[nt * 16 + l][quad * 8];
      bf16x8 kf1 = *(const bf16x8*)&Ke[nt * 16 + l][32 + quad * 8];
      #pragma unroll
      for (int s = 0; s < 2; s++) {
        int iblk = i0 + (wave * 2 + s) * 16;  // min i of this 16-row block
        int jb = j0v + nt * 16;               // min j of this 16-col tile
        uint2 pk;
        if (jb > iblk + 15) {                 // fully masked: skip all math
          pk.x = 0u; pk.y = 0u;
        } else {
          f32x4 sv = (f32x4){0.f, 0.f, 0.f, 0.f};
          sv = __builtin_amdgcn_mfma_f32_16x16x32_bf16(kf0, qf[s][0], sv, 0, 0, 0);
          sv = __builtin_amdgcn_mfma_f32_16x16x32_bf16(kf1, qf[s][1], sv, 0, 0, 0);
          float p0, p1, p2, p3;
          if (jb + 15 <= iblk) {              // fully unmasked: no compares
            p0 = __builtin_amdgcn_exp2f(sv[0] * cs);
            p1 = __builtin_amdgcn_exp2f(sv[1] * cs);
            p2 = __builtin_amdgcn_exp2f(sv[2] * cs);
            p3 = __builtin_amdgcn_exp2f(sv[3] * cs);
          } else {                            // straddling: per-element mask
            int i_ = iblk + l, jbase = jb + quad * 4;
            p0 = (jbase + 0 > i_) ? 0.f : __builtin_amdgcn_exp2f(sv[0] * cs);
            p1 = (jbase + 1 > i_) ? 0.f : __builtin_amdgcn_exp2f(sv[1] * cs);
            p2 = (jbase + 2 > i_) ? 0.f : __builtin_amdgcn_exp2f(sv[2] * cs);
            p3 = (jbase + 3 > i_) ? 0.f : __builtin_amdgcn_exp2f(sv[3] * cs);
          }
          lsum[s] += (p0 + p1) + (p2 + p3);
          union { __hip_bfloat162 h2; unsigned u; } c0u, c1u;
          c0u.h2 = __float22bfloat162_rn(make_float2(p0, p1));
          c1u.h2 = __float22bfloat162_rn(make_float2(p2, p3));
          pk.x = c0u.u; pk.y = c1u.u;
        }
        *(uint2*)&QP[(wave * 2 + s) * 16 + l][nt * 16 + quad * 4] = pk;
      }
    }
    asm volatile("s_waitcnt lgkmcnt(0)" ::: "memory");  // own-wave P rows only

    bf16x8 ap[2][2];
    #pragma unroll
    for (int s = 0; s < 2; s++) {
      int rowp = (wave * 2 + s) * 16 + l;
      ap[s][0] = *(const bf16x8*)&QP[rowp][quad * 8];
      ap[s][1] = *(const bf16x8*)&QP[rowp][32 + quad * 8];
    }
    #pragma unroll
    for (int dt = 0; dt < 4; dt++) {
      bf16x8 bv0 = *(const bf16x8*)&Vt[dt * 16 + l][quad * 8];
      bf16x8 bv1 = *(const bf16x8*)&Vt[dt * 16 + l][32 + quad * 8];
      #pragma unroll
      for (int s = 0; s < 2; s++) {
        Oacc[s][dt] = __builtin_amdgcn_mfma_f32_16x16x32_bf16(ap[s][0], bv0, Oacc[s][dt], 0, 0, 0);
        Oacc[s][dt] = __builtin_amdgcn_mfma_f32_16x16x32_bf16(ap[s][1], bv1, Oacc[s][dt], 0, 0, 0);
      }
    }
  }

  #pragma unroll
  for (int s = 0; s < 2; s++) {
    lsum[s] += __shfl_xor(lsum[s], 16);
    lsum[s] += __shfl_xor(lsum[s], 32);
  }
  #pragma unroll
  for (int s = 0; s < 2; s++) {
    #pragma unroll
    for (int r = 0; r < 4; r++) {
      float lv = __shfl(lsum[s], quad * 4 + r);
      float inv = 1.0f / lv;
      int row = i0 + (wave * 2 + s) * 16 + quad * 4 + r;
      size_t gi = qk_base + (size_t)row * 1024;
      #pragma unroll
      for (int dt = 0; dt < 4; dt++) {
        int d = dt * 16 + l;
        x1[gi + d] = x[gi + d] + Oacc[s][dt][r] * inv;
      }
    }
  }
}

extern "C" void kernel_launch(void* const* d_in, const int* in_sizes, int n_in,
                              void* d_out, int out_size, void* d_ws, size_t ws_size,
                              hipStream_t stream) {
  const float* x    = (const float*)d_in[0];
  const float* ln1g = (const float*)d_in[1];
  const float* ln1b = (const float*)d_in[2];
  const float* Wq   = (const float*)d_in[3];
  const float* bq   = (const float*)d_in[4];
  const float* Wk   = (const float*)d_in[5];
  const float* bk   = (const float*)d_in[6];
  const float* Wv   = (const float*)d_in[7];
  const float* bv   = (const float*)d_in[8];
  const float* ln2g = (const float*)d_in[9];
  const float* ln2b = (const float*)d_in[10];
  const float* W1   = (const float*)d_in[11];
  const float* b1   = (const float*)d_in[12];
  const float* W2   = (const float*)d_in[13];
  const float* b2   = (const float*)d_in[14];

  char* ws = (char*)d_ws;
  float* x1  = (float*)(ws + 0);            // 16 MB f32 [4096][1024]
  bf16* h    = (bf16*)(ws + 16777216);      //  8 MB bf16 [4096][1024]
  bf16* WqkT = (bf16*)(ws + 25165824);      //  6 MB bf16 [3072][1024] (q|k|v)
  bf16* W1T  = (bf16*)(ws + 31457280);      //  8 MB [4096][1024]
  bf16* W2T  = (bf16*)(ws + 39845888);      //  8 MB [1024][4096]
  bf16* qb   = (bf16*)(ws + 48234496);      //  8 MB [4096][1024]  (reused: FFN2 partial 0)
  bf16* kb   = (bf16*)(ws + 56623104);      //  8 MB [4096][1024]  (reused: FFN2 partial 1)
  bf16* vt   = (bf16*)(ws + 65011712);      //  8 MB [b,h,d,t] = [2048][2048]
  bf16* act  = (bf16*)(ws + 73400320);      // 32 MB [4096][4096]

  transpose_all<<<11264, 256, 0, stream>>>(Wq, Wk, Wv, W1, W2, WqkT, W1T, W2T);
  ln_kernel<<<4096, 256, 0, stream>>>(x, ln1g, ln1b, h);
  gemm_qkv<<<dim3(24, 32), 256, 0, stream>>>(h, WqkT, bq, bk, bv, qb, kb, vt, 1024);
  attn_mfma<<<dim3(32, 16), 256, 0, stream>>>(qb, kb, vt, x, x1);
  ln_kernel<<<4096, 256, 0, stream>>>(x1, ln2g, ln2b, h);
  gemm_ffn1<<<dim3(32, 32), 256, 0, stream>>>(h, W1T, b1, act, 4096, 1024);
  gemm_ffn2_sk<<<dim3(8, 32, 2), 256, 0, stream>>>(act, W2T,
      (unsigned short*)qb, (unsigned short*)kb, 4096);
  reduce_ffn2<<<4096, 256, 0, stream>>>((const unsigned short*)qb, (const unsigned short*)kb,
                                        x1, b2, (float*)d_out);
}

// Round 9
// 318.420 us; speedup vs baseline: 1.1312x; 1.1312x over previous
//
#include <hip/hip_runtime.h>
#include <hip/hip_bf16.h>
#include <math.h>

typedef __hip_bfloat16 bf16;
typedef __attribute__((ext_vector_type(8))) short bf16x8;
typedef __attribute__((ext_vector_type(4))) float f32x4;

__device__ __forceinline__ unsigned short f2bf_rne(float f) {
  unsigned u = __float_as_uint(f);
  u += 0x7fffu + ((u >> 16) & 1u);
  return (unsigned short)(u >> 16);
}
__device__ __forceinline__ float bf2f(unsigned short s) {
  return __uint_as_float(((unsigned)s) << 16);
}

// fast tanh-form GELU: max |diff| vs exact erf-GELU ~1e-3
__device__ __forceinline__ float gelu_fast(float v) {
  float u = v * (0.7978845608f + 0.0356774081f * v * v);
  float t = __builtin_amdgcn_exp2f(u * 2.8853900818f);
  float r = __builtin_amdgcn_rcpf(t + 1.0f);
  return v - v * r;
}

#define GLOBAL_AS __attribute__((address_space(1)))
#define LDS_AS __attribute__((address_space(3)))
__device__ __forceinline__ void gl2lds16(const void* g, void* l) {
  __builtin_amdgcn_global_load_lds((const GLOBAL_AS void*)g, (LDS_AS void*)l, 16, 0, 0);
}

// ---------------- LayerNorm: x f32 [rows][1024] -> h bf16 ----------------
__global__ __launch_bounds__(256) void ln_kernel(const float* __restrict__ x,
                                                 const float* __restrict__ g,
                                                 const float* __restrict__ b,
                                                 bf16* __restrict__ h) {
  int row = blockIdx.x, t = threadIdx.x;
  const float4 xv = ((const float4*)(x + (size_t)row * 1024))[t];
  float s = xv.x + xv.y + xv.z + xv.w;
  float sq = xv.x * xv.x + xv.y * xv.y + xv.z * xv.z + xv.w * xv.w;
  #pragma unroll
  for (int m = 1; m < 64; m <<= 1) { s += __shfl_xor(s, m); sq += __shfl_xor(sq, m); }
  __shared__ float ps[4], pq[4];
  if ((t & 63) == 0) { ps[t >> 6] = s; pq[t >> 6] = sq; }
  __syncthreads();
  s = ps[0] + ps[1] + ps[2] + ps[3];
  sq = pq[0] + pq[1] + pq[2] + pq[3];
  float mean = s * (1.0f / 1024.0f);
  float var = sq * (1.0f / 1024.0f) - mean * mean;
  float rs = rsqrtf(var + 1e-3f);
  float4 gv = ((const float4*)g)[t];
  float4 bv = ((const float4*)b)[t];
  ushort4 o;
  o.x = f2bf_rne((xv.x - mean) * rs * gv.x + bv.x);
  o.y = f2bf_rne((xv.y - mean) * rs * gv.y + bv.y);
  o.z = f2bf_rne((xv.z - mean) * rs * gv.z + bv.z);
  o.w = f2bf_rne((xv.w - mean) * rs * gv.w + bv.w);
  ((ushort4*)(h + (size_t)row * 1024))[t] = o;
}

// ------------- merged transpose + f32->bf16 for all 5 weights -------------
__device__ __forceinline__ void tr_tile(const float* __restrict__ W, bf16* __restrict__ WT,
                                        int R, int Cc, int bx, int by, int t) {
  __shared__ float tile[32][33];
  int tx = t & 31, ty = t >> 5;
  #pragma unroll
  for (int k = 0; k < 4; k++) {
    int rr = ty + k * 8;
    tile[rr][tx] = W[(size_t)(by + rr) * Cc + bx + tx];
  }
  __syncthreads();
  unsigned short* out = reinterpret_cast<unsigned short*>(WT);
  #pragma unroll
  for (int k = 0; k < 4; k++) {
    int rr = ty + k * 8;
    out[(size_t)(bx + rr) * R + by + tx] = f2bf_rne(tile[tx][rr]);
  }
}

__global__ __launch_bounds__(256) void transpose_all(const float* __restrict__ Wq,
                                                     const float* __restrict__ Wk,
                                                     const float* __restrict__ Wv,
                                                     const float* __restrict__ W1,
                                                     const float* __restrict__ W2,
                                                     bf16* __restrict__ WqkT,
                                                     bf16* __restrict__ W1T,
                                                     bf16* __restrict__ W2T) {
  int id = blockIdx.x, t = threadIdx.x;
  if (id < 3072) {
    int sect = id >> 10, r = id & 1023;
    const float* W = sect == 0 ? Wq : (sect == 1 ? Wk : Wv);
    bf16* WT = WqkT + (size_t)sect * 1048576;
    tr_tile(W, WT, 1024, 1024, (r & 31) * 32, (r >> 5) * 32, t);
  } else if (id < 7168) {
    int r = id - 3072;
    tr_tile(W1, W1T, 1024, 4096, (r & 127) * 32, (r >> 7) * 32, t);
  } else {
    int r = id - 7168;
    tr_tile(W2, W2T, 4096, 1024, (r & 31) * 32, (r >> 5) * 32, t);
  }
}

// ---------- shared K-loop: 128x128 tile, BK=64, async staging, XOR swizzle ----
__device__ __forceinline__ void kloop_bk64(const bf16* __restrict__ A,
                                           const bf16* __restrict__ BT,
                                           int K, int kbeg, int kend, int m0, int n0,
                                           int wave, int lane,
                                           bf16 (*As)[64], bf16 (*Bs)[64],
                                           f32x4 acc[4][4]) {
  int lrow = lane & 15, quad = lane >> 4;
  int wm = (wave >> 1) * 64, wn = (wave & 1) * 64;
  int srow = wave * 32 + (lane >> 3);
  int gsw = ((lane & 7) ^ (lane >> 3)) * 8;
  int sw = lrow & 7;
  for (int k0 = kbeg; k0 < kend; k0 += 64) {
    __syncthreads();
    #pragma unroll
    for (int j = 0; j < 4; j++) {
      int row = srow + j * 8;
      gl2lds16(A + (size_t)(m0 + row) * K + k0 + gsw, (char*)As + wave * 4096 + j * 1024);
      gl2lds16(BT + (size_t)(n0 + row) * K + k0 + gsw, (char*)Bs + wave * 4096 + j * 1024);
    }
    __syncthreads();
    bf16x8 af[2][4], bfr[2][4];
    #pragma unroll
    for (int h = 0; h < 2; h++) {
      #pragma unroll
      for (int i = 0; i < 4; i++)
        af[h][i] = *(const bf16x8*)((const char*)&As[wm + i * 16 + lrow][0] +
                                    (((h * 4 + quad) ^ sw) * 16));
      #pragma unroll
      for (int j = 0; j < 4; j++)
        bfr[h][j] = *(const bf16x8*)((const char*)&Bs[wn + j * 16 + lrow][0] +
                                     (((h * 4 + quad) ^ sw) * 16));
    }
    #pragma unroll
    for (int h = 0; h < 2; h++)
      #pragma unroll
      for (int i = 0; i < 4; i++)
        #pragma unroll
        for (int j = 0; j < 4; j++)
          acc[i][j] = __builtin_amdgcn_mfma_f32_16x16x32_bf16(af[h][i], bfr[h][j], acc[i][j], 0, 0, 0);
  }
}

// ---------------- FFN1: act bf16 = gelu(h @ W1 + b1), N=4096 K=1024 ---------
__global__ __launch_bounds__(256) void gemm_ffn1(const bf16* __restrict__ A,
                                                 const bf16* __restrict__ BT,
                                                 const float* __restrict__ bias,
                                                 bf16* __restrict__ out,
                                                 int N, int K) {
  __shared__ bf16 As[128][64];
  __shared__ bf16 Bs[128][64];
  int t = threadIdx.x;
  int n0 = blockIdx.x * 128, m0 = blockIdx.y * 128;
  int lane = t & 63, wave = t >> 6;
  f32x4 acc[4][4];
  #pragma unroll
  for (int i = 0; i < 4; i++)
    #pragma unroll
    for (int j = 0; j < 4; j++) acc[i][j] = (f32x4){0.f, 0.f, 0.f, 0.f};
  kloop_bk64(A, BT, K, 0, K, m0, n0, wave, lane, As, Bs, acc);

  int wm = (wave >> 1) * 64, wn = (wave & 1) * 64;
  int r4 = (lane >> 4) * 4, cl = lane & 15;
  unsigned short* os = reinterpret_cast<unsigned short*>(out);
  #pragma unroll
  for (int i = 0; i < 4; i++)
    #pragma unroll
    for (int j = 0; j < 4; j++) {
      int col = n0 + wn + j * 16 + cl;
      float bval = bias[col];
      #pragma unroll
      for (int r = 0; r < 4; r++) {
        int row = m0 + wm + i * 16 + r4 + r;
        os[(size_t)row * N + col] = f2bf_rne(gelu_fast(acc[i][j][r] + bval));
      }
    }
}

// ------- FFN2 split-K: partial bf16 = act[:, kslice] @ W2[kslice, :] --------
__global__ __launch_bounds__(256) void gemm_ffn2_sk(const bf16* __restrict__ A,
                                                    const bf16* __restrict__ BT,
                                                    unsigned short* __restrict__ p0,
                                                    unsigned short* __restrict__ p1,
                                                    int K) {
  __shared__ bf16 As[128][64];
  __shared__ bf16 Bs[128][64];
  int t = threadIdx.x;
  int n0 = blockIdx.x * 128, m0 = blockIdx.y * 128;
  int z = blockIdx.z;
  int lane = t & 63, wave = t >> 6;
  f32x4 acc[4][4];
  #pragma unroll
  for (int i = 0; i < 4; i++)
    #pragma unroll
    for (int j = 0; j < 4; j++) acc[i][j] = (f32x4){0.f, 0.f, 0.f, 0.f};
  kloop_bk64(A, BT, K, z * 2048, z * 2048 + 2048, m0, n0, wave, lane, As, Bs, acc);

  unsigned short* p = z ? p1 : p0;
  int wm = (wave >> 1) * 64, wn = (wave & 1) * 64;
  int r4 = (lane >> 4) * 4, cl = lane & 15;
  #pragma unroll
  for (int i = 0; i < 4; i++)
    #pragma unroll
    for (int j = 0; j < 4; j++) {
      int col = n0 + wn + j * 16 + cl;
      #pragma unroll
      for (int r = 0; r < 4; r++) {
        int row = m0 + wm + i * 16 + r4 + r;
        p[(size_t)row * 1024 + col] = f2bf_rne(acc[i][j][r]);
      }
    }
}

// -------- FFN2 reduce: out f32 = p0 + p1 + bias + x1 --------
__global__ __launch_bounds__(256) void reduce_ffn2(const unsigned short* __restrict__ p0,
                                                   const unsigned short* __restrict__ p1,
                                                   const float* __restrict__ x1,
                                                   const float* __restrict__ bias,
                                                   float* __restrict__ out) {
  int row = blockIdx.x, t = threadIdx.x;
  size_t base = (size_t)row * 1024;
  ushort4 a = ((const ushort4*)(p0 + base))[t];
  ushort4 b = ((const ushort4*)(p1 + base))[t];
  float4 xv = ((const float4*)(x1 + base))[t];
  float4 bv = ((const float4*)bias)[t];
  float4 o;
  o.x = bf2f(a.x) + bf2f(b.x) + xv.x + bv.x;
  o.y = bf2f(a.y) + bf2f(b.y) + xv.y + bv.y;
  o.z = bf2f(a.z) + bf2f(b.z) + xv.z + bv.z;
  o.w = bf2f(a.w) + bf2f(b.w) + xv.w + bv.w;
  ((float4*)(out + base))[t] = o;
}

// ------------- fused QKV GEMM: N=3072 (q|k|v); v written transposed ----------
__global__ __launch_bounds__(256) void gemm_qkv(const bf16* __restrict__ A,
                                                const bf16* __restrict__ BT,
                                                const float* __restrict__ bq,
                                                const float* __restrict__ bk,
                                                const float* __restrict__ bv,
                                                bf16* __restrict__ qb,
                                                bf16* __restrict__ kb,
                                                bf16* __restrict__ vt,
                                                int K) {
  __shared__ bf16 As[128][64];
  __shared__ bf16 Bs[128][64];
  int t = threadIdx.x;
  int n0 = blockIdx.x * 128, m0 = blockIdx.y * 128;
  int lane = t & 63, wave = t >> 6;
  f32x4 acc[4][4];
  #pragma unroll
  for (int i = 0; i < 4; i++)
    #pragma unroll
    for (int j = 0; j < 4; j++) acc[i][j] = (f32x4){0.f, 0.f, 0.f, 0.f};
  kloop_bk64(A, BT, K, 0, K, m0, n0, wave, lane, As, Bs, acc);

  int sect = n0 >> 10;  // 0=q 1=k 2=v
  const float* bias = sect == 0 ? bq : (sect == 1 ? bk : bv);
  int wm = (wave >> 1) * 64, wn = (wave & 1) * 64;
  int r4 = (lane >> 4) * 4, cl = lane & 15;
  #pragma unroll
  for (int i = 0; i < 4; i++)
    #pragma unroll
    for (int j = 0; j < 4; j++) {
      int col = n0 + wn + j * 16 + cl;
      int c1 = col & 1023;
      float bval = bias[c1];
      int row0 = m0 + wm + i * 16 + r4;
      if (sect < 2) {
        bf16* o = sect == 0 ? qb : kb;
        unsigned short* os = reinterpret_cast<unsigned short*>(o);
        #pragma unroll
        for (int r = 0; r < 4; r++)
          os[(size_t)(row0 + r) * 1024 + c1] = f2bf_rne(acc[i][j][r] + bval);
      } else {
        int hh = c1 >> 6, d = c1 & 63;
        int b = row0 >> 11, t0 = row0 & 2047;
        ushort4 pk;
        pk.x = f2bf_rne(acc[i][j][0] + bval);
        pk.y = f2bf_rne(acc[i][j][1] + bval);
        pk.z = f2bf_rne(acc[i][j][2] + bval);
        pk.w = f2bf_rne(acc[i][j][3] + bval);
        *(ushort4*)((unsigned short*)vt + (size_t)((b * 16 + hh) * 64 + d) * 2048 + t0) = pk;
      }
    }
}

// ---------------- MFMA flash attention v4 ----------------
// 64-row i-tile per pass, in-block pass pairing (it, 31-it) -> uniform 33
// j-units/block, grid (32,16)=512 blocks = 2/CU (LDS 41KB allows 3).
// KV double-buffered via global_load_lds (XOR-swizzled) -> ONE barrier per
// j-tile; prefetch of tile jt+1 overlaps compute on jt.
__global__ __launch_bounds__(256) void attn_mfma(const bf16* __restrict__ qb,
                                                 const bf16* __restrict__ kb,
                                                 const bf16* __restrict__ vt,
                                                 const float* __restrict__ x,
                                                 float* __restrict__ x1) {
  __shared__ bf16 QP[64][72];        // Q in prologue, then P (padded layout)
  __shared__ bf16 KV[2][2][64][64];  // [buf][0=K,1=V], XOR-swizzled 16B groups
  int t = threadIdx.x;
  int bh = blockIdx.x;
  int b = bh >> 4, h = bh & 15;
  size_t qk_base = (size_t)b * 2048 * 1024 + (size_t)h * 64;
  size_t vt_base = (size_t)bh * 64 * 2048;
  int lane = t & 63, wave = t >> 6;
  int l = lane & 15, quad = lane >> 4;
  int sw = l & 7;
  int srow8 = lane >> 3;                       // staging row-in-8 (0..7)
  int scol = ((lane & 7) ^ srow8) * 8;         // swizzled source col (elems)
  const float cs = 0.125f * 1.44269504088896f; // scale * log2(e)
  int y = blockIdx.y;

  for (int pass = 0; pass < 2; pass++) {
    int it = pass ? 31 - y : y;
    int i0 = it * 64;
    int njt = it + 1;
    __syncthreads();  // LDS reuse across passes
    // stage Q (this i-tile's K rows) into QP
    #pragma unroll
    for (int c0 = 0; c0 < 512; c0 += 256) {
      int c = c0 + t;
      int row = c >> 3, col8 = (c & 7) * 8;
      *(uint4*)&QP[row][col8] = *(const uint4*)(kb + qk_base + (size_t)(i0 + row) * 1024 + col8);
    }
    // stage KV tile 0 into buf 0 (async, swizzled)
    #pragma unroll
    for (int c = 0; c < 2; c++) {
      int rr = wave * 16 + c * 8 + srow8;
      gl2lds16(qb + qk_base + (size_t)rr * 1024 + scol,
               (char*)KV + wave * 2048 + c * 1024);
      gl2lds16(vt + vt_base + (size_t)rr * 2048 + scol,
               (char*)KV + 8192 + wave * 2048 + c * 1024);
    }
    __syncthreads();  // compiler inserts vmcnt(0): Q + KV0 visible

    bf16x8 qf0 = *(const bf16x8*)&QP[wave * 16 + l][quad * 8];
    bf16x8 qf1 = *(const bf16x8*)&QP[wave * 16 + l][32 + quad * 8];
    float lsum = 0.f;
    f32x4 Oacc[4];
    #pragma unroll
    for (int dt = 0; dt < 4; dt++) Oacc[dt] = (f32x4){0.f, 0.f, 0.f, 0.f};
    int iblk = i0 + wave * 16;

    int buf = 0;
    for (int jt = 0; jt < njt; jt++) {
      int j0v = jt * 64;
      // prefetch next KV tile into other buffer (overlaps with compute below)
      if (jt + 1 < njt) {
        int j1 = j0v + 64;
        #pragma unroll
        for (int c = 0; c < 2; c++) {
          int rr = wave * 16 + c * 8 + srow8;
          gl2lds16(qb + qk_base + (size_t)(j1 + rr) * 1024 + scol,
                   (char*)KV + (buf ^ 1) * 16384 + wave * 2048 + c * 1024);
          gl2lds16(vt + vt_base + (size_t)rr * 2048 + j1 + scol,
                   (char*)KV + (buf ^ 1) * 16384 + 8192 + wave * 2048 + c * 1024);
        }
      }

      // S^T per nt: A = K rows (m=j), B = Q frag (n=i)
      const bf16* Kb = &KV[buf][0][0][0];
      #pragma unroll
      for (int nt = 0; nt < 4; nt++) {
        int jb = j0v + nt * 16;
        uint2 pk;
        if (jb > iblk + 15) {  // fully masked
          pk.x = 0u; pk.y = 0u;
        } else {
          const bf16* kr = Kb + (nt * 16 + l) * 64;
          bf16x8 kf0 = *(const bf16x8*)(kr + ((quad ^ sw) * 8));
          bf16x8 kf1 = *(const bf16x8*)(kr + (((4 + quad) ^ sw) * 8));
          f32x4 sv = (f32x4){0.f, 0.f, 0.f, 0.f};
          sv = __builtin_amdgcn_mfma_f32_16x16x32_bf16(kf0, qf0, sv, 0, 0, 0);
          sv = __builtin_amdgcn_mfma_f32_16x16x32_bf16(kf1, qf1, sv, 0, 0, 0);
          float p0, p1, p2, p3;
          if (jb + 15 <= iblk) {  // fully unmasked
            p0 = __builtin_amdgcn_exp2f(sv[0] * cs);
            p1 = __builtin_amdgcn_exp2f(sv[1] * cs);
            p2 = __builtin_amdgcn_exp2f(sv[2] * cs);
            p3 = __builtin_amdgcn_exp2f(sv[3] * cs);
          } else {                // diagonal straddle
            int i_ = iblk + l, jbase = jb + quad * 4;
            p0 = (jbase + 0 > i_) ? 0.f : __builtin_amdgcn_exp2f(sv[0] * cs);
            p1 = (jbase + 1 > i_) ? 0.f : __builtin_amdgcn_exp2f(sv[1] * cs);
            p2 = (jbase + 2 > i_) ? 0.f : __builtin_amdgcn_exp2f(sv[2] * cs);
            p3 = (jbase + 3 > i_) ? 0.f : __builtin_amdgcn_exp2f(sv[3] * cs);
          }
          lsum += (p0 + p1) + (p2 + p3);
          union { __hip_bfloat162 h2; unsigned u; } c0u, c1u;
          c0u.h2 = __float22bfloat162_rn(make_float2(p0, p1));
          c1u.h2 = __float22bfloat162_rn(make_float2(p2, p3));
          pk.x = c0u.u; pk.y = c1u.u;
        }
        *(uint2*)&QP[wave * 16 + l][nt * 16 + quad * 4] = pk;
      }
      asm volatile("s_waitcnt lgkmcnt(0)" ::: "memory");  // own-wave P only

      // PV: A = P rows (m=i), B = V rows (n=d)
      bf16x8 ap0 = *(const bf16x8*)&QP[wave * 16 + l][quad * 8];
      bf16x8 ap1 = *(const bf16x8*)&QP[wave * 16 + l][32 + quad * 8];
      const bf16* Vb = &KV[buf][1][0][0];
      #pragma unroll
      for (int dt = 0; dt < 4; dt++) {
        const bf16* vr = Vb + (dt * 16 + l) * 64;
        bf16x8 bv0 = *(const bf16x8*)(vr + ((quad ^ sw) * 8));
        bf16x8 bv1 = *(const bf16x8*)(vr + (((4 + quad) ^ sw) * 8));
        Oacc[dt] = __builtin_amdgcn_mfma_f32_16x16x32_bf16(ap0, bv0, Oacc[dt], 0, 0, 0);
        Oacc[dt] = __builtin_amdgcn_mfma_f32_16x16x32_bf16(ap1, bv1, Oacc[dt], 0, 0, 0);
      }
      __syncthreads();  // drains prefetch (vmcnt) + all waves done with buf
      buf ^= 1;
    }

    // denominator: sum over quads (each lane's lsum is i=l partial)
    lsum += __shfl_xor(lsum, 16);
    lsum += __shfl_xor(lsum, 32);
    #pragma unroll
    for (int r = 0; r < 4; r++) {
      float lv = __shfl(lsum, quad * 4 + r);
      float inv = 1.0f / lv;
      int row = i0 + wave * 16 + quad * 4 + r;
      size_t gi = qk_base + (size_t)row * 1024;
      #pragma unroll
      for (int dt = 0; dt < 4; dt++) {
        int d = dt * 16 + l;
        x1[gi + d] = x[gi + d] + Oacc[dt][r] * inv;
      }
    }
  }
}

extern "C" void kernel_launch(void* const* d_in, const int* in_sizes, int n_in,
                              void* d_out, int out_size, void* d_ws, size_t ws_size,
                              hipStream_t stream) {
  const float* x    = (const float*)d_in[0];
  const float* ln1g = (const float*)d_in[1];
  const float* ln1b = (const float*)d_in[2];
  const float* Wq   = (const float*)d_in[3];
  const float* bq   = (const float*)d_in[4];
  const float* Wk   = (const float*)d_in[5];
  const float* bk   = (const float*)d_in[6];
  const float* Wv   = (const float*)d_in[7];
  const float* bv   = (const float*)d_in[8];
  const float* ln2g = (const float*)d_in[9];
  const float* ln2b = (const float*)d_in[10];
  const float* W1   = (const float*)d_in[11];
  const float* b1   = (const float*)d_in[12];
  const float* W2   = (const float*)d_in[13];
  const float* b2   = (const float*)d_in[14];

  char* ws = (char*)d_ws;
  float* x1  = (float*)(ws + 0);            // 16 MB f32 [4096][1024]
  bf16* h    = (bf16*)(ws + 16777216);      //  8 MB bf16 [4096][1024]
  bf16* WqkT = (bf16*)(ws + 25165824);      //  6 MB bf16 [3072][1024] (q|k|v)
  bf16* W1T  = (bf16*)(ws + 31457280);      //  8 MB [4096][1024]
  bf16* W2T  = (bf16*)(ws + 39845888);      //  8 MB [1024][4096]
  bf16* qb   = (bf16*)(ws + 48234496);      //  8 MB [4096][1024]  (reused: FFN2 partial 0)
  bf16* kb   = (bf16*)(ws + 56623104);      //  8 MB [4096][1024]  (reused: FFN2 partial 1)
  bf16* vt   = (bf16*)(ws + 65011712);      //  8 MB [b,h,d,t] = [2048][2048]
  bf16* act  = (bf16*)(ws + 73400320);      // 32 MB [4096][4096]

  transpose_all<<<11264, 256, 0, stream>>>(Wq, Wk, Wv, W1, W2, WqkT, W1T, W2T);
  ln_kernel<<<4096, 256, 0, stream>>>(x, ln1g, ln1b, h);
  gemm_qkv<<<dim3(24, 32), 256, 0, stream>>>(h, WqkT, bq, bk, bv, qb, kb, vt, 1024);
  attn_mfma<<<dim3(32, 16), 256, 0, stream>>>(qb, kb, vt, x, x1);
  ln_kernel<<<4096, 256, 0, stream>>>(x1, ln2g, ln2b, h);
  gemm_ffn1<<<dim3(32, 32), 256, 0, stream>>>(h, W1T, b1, act, 4096, 1024);
  gemm_ffn2_sk<<<dim3(8, 32, 2), 256, 0, stream>>>(act, W2T,
      (unsigned short*)qb, (unsigned short*)kb, 4096);
  reduce_ffn2<<<4096, 256, 0, stream>>>((const unsigned short*)qb, (const unsigned short*)kb,
                                        x1, b2, (float*)d_out);
}